// Round 1
// baseline (144.191 us; speedup 1.0000x reference)
//
#include <hip/hip_runtime.h>

typedef _Float16 f16x8 __attribute__((ext_vector_type(8)));
typedef float    f32x4 __attribute__((ext_vector_type(4)));

namespace {
constexpr int Bb = 8, Cc = 256, Oo = 256;
constexpr int HW = 4096;                 // 64x64
constexpr int NCH2 = 36;                 // double-chunks of 64 K (4 per tap)
constexpr int SROW2 = 72;                // Sl row stride (f16): 64 + 8 pad
constexpr int TBLK = 512;                // transpose blocks (8 b x 64 px-groups)
}

__device__ inline f16x8 sp8(_Float16 x) { f16x8 r = {x,x,x,x,x,x,x,x}; return r; }

// Raw barrier: drain LDS ops only (stage ds_write visibility), leave global
// gathers / A-frag loads in flight across the barrier (vmcnt uncounted).
// __syncthreads() would force s_waitcnt vmcnt(0) and kill the prefetch.
__device__ __forceinline__ void barrier_lgkm() {
  asm volatile("s_waitcnt lgkmcnt(0)" ::: "memory");
  __builtin_amdgcn_s_barrier();
}

// ---------- fused pre-kernel (R10 verbatim) ----------
__global__ __launch_bounds__(256)
void prep(const float* __restrict__ in, const float* __restrict__ w,
          _Float16* __restrict__ outh, _Float16* __restrict__ wh) {
  const int bid = blockIdx.x;
  const int t   = threadIdx.x;
  if (bid < TBLK) {
    __shared__ _Float16 Lt[64][264];
    const int b = bid >> 6, pxg = bid & 63;
    const float* src = in + (size_t)b * Cc * HW + pxg * 64;
    const int chb = t & 15, quad = t >> 4;
#pragma unroll
    for (int ci = 0; ci < 16; ++ci) {
      int ch = ci * 16 + chb;
      float4 v = *(const float4*)(src + (size_t)ch * HW + quad * 4);
      Lt[quad * 4 + 0][ch] = (_Float16)v.x;
      Lt[quad * 4 + 1][ch] = (_Float16)v.y;
      Lt[quad * 4 + 2][ch] = (_Float16)v.z;
      Lt[quad * 4 + 3][ch] = (_Float16)v.w;
    }
    __syncthreads();
    _Float16* dst = outh + ((size_t)b * HW + pxg * 64) * Cc;
    const int c8 = t & 31, pxs = t >> 5;
#pragma unroll
    for (int it = 0; it < 8; ++it) {
      int px = it * 8 + pxs;
      f16x8 v = *(const f16x8*)(&Lt[px][c8 * 8]);
      *(f16x8*)(dst + (size_t)px * Cc + c8 * 8) = v;
    }
  } else {
    int tt = (bid - TBLK) * 256 + t;
    int o  = tt & 255;
    int Kb = (tt >> 8) * 8;
    const float* s = w + (size_t)o * 2304;
    f16x8 v;
#pragma unroll
    for (int k8 = 0; k8 < 8; ++k8) {
      int K = Kb + k8;
      int tap = K >> 8, c = K & 255;
      v[k8] = (_Float16)s[c * 9 + tap];
    }
    *(f16x8*)(wh + (size_t)tt * 8) = v;
  }
}

// ---------- main kernel: 256(o) x 64(p), chunk = 64 K, 36 raw barriers ----------
__global__ __launch_bounds__(256, 2)
void dcn_mfma(const _Float16* __restrict__ inh,   // [B][4096][256] fp16 NHWC
              const _Float16* __restrict__ wgh,   // [72][4][256][8] fp16 (A-frag order)
              const float* __restrict__ offset,
              const float* __restrict__ mask,
              const float* __restrict__ bias,
              float* __restrict__ out) {
  __shared__ __align__(16) _Float16 Sl[2][64 * SROW2];  // 18.4 KB

  const int tid = threadIdx.x;
  const int b   = blockIdx.x;   // 0..7  -> linear%8 -> XCD-affine batch
  const int rp  = blockIdx.y;   // 0..63 -> one output row

  const int pos = tid >> 2, cg = tid & 3;
  const int ho  = rp, wo = pos;
  const int lane = tid & 63, wm = tid >> 6;
  const int lq = lane >> 4, lr = lane & 15;

  const f16x8* gin = (const f16x8*)(inh + (size_t)b * HW * Cc);
  const uint4* wg4 = (const uint4*)wgh;
  const int    wbase = lq * 256 + wm * 64 + lr;

  int4   mi_c, mi_n = {0,0,0,0};
  float4 mwt_c, mwt_n = {0,0,0,0};
  float  ofy, ofx, msk;
  f16x8  vc[2][8];               // depth-2 corner sets, 8 octets (2 per corner)
  uint4  awv[8];                 // A-fragments in flight (both K-halves)

  auto load_md_inputs = [&](int tap) {
    ofy = offset[(((size_t)b * 18 + 2 * tap)     * 64 + ho) * 64 + wo];
    ofx = offset[(((size_t)b * 18 + 2 * tap + 1) * 64 + ho) * 64 + wo];
    msk = mask  [(((size_t)b * 9  + tap)         * 64 + ho) * 64 + wo];
  };
  auto build_md = [&](int tap, int4& mio, float4& mwo) {
    int ki = tap / 3, kj = tap % 3;
    float y = ofy + (float)(ho - 1 + ki);
    float x = ofx + (float)(wo - 1 + kj);
    float y0f = floorf(y), x0f = floorf(x);
    float ly = y - y0f, lx = x - x0f;
    float hy = 1.f - ly, hx = 1.f - lx;
    int y0 = (int)y0f, x0 = (int)x0f;
    int y1 = y0 + 1, x1 = x0 + 1;
    bool vy0 = (unsigned)y0 < 64u, vy1 = (unsigned)y1 < 64u;
    bool vx0 = (unsigned)x0 < 64u, vx1 = (unsigned)x1 < 64u;
    int cy0 = min(max(y0, 0), 63), cy1 = min(max(y1, 0), 63);
    int cx0 = min(max(x0, 0), 63), cx1 = min(max(x1, 0), 63);
    mwo.x = (vy0 && vx0) ? hy * hx * msk : 0.f;
    mwo.y = (vy0 && vx1) ? hy * lx * msk : 0.f;
    mwo.z = (vy1 && vx0) ? ly * hx * msk : 0.f;
    mwo.w = (vy1 && vx1) ? ly * lx * msk : 0.f;
    mio = make_int4(cy0 * 64 + cx0, cy0 * 64 + cx1, cy1 * 64 + cx0, cy1 * 64 + cx1);
  };
  // gather 64 channels (2 octets per corner) for double-chunk cc
  auto gather = [&](const int4& m, int cc, f16x8* dst) {
    int cb = (cc & 3) * 8 + cg;
    dst[0] = gin[m.x * 32 + cb];     dst[1] = gin[m.y * 32 + cb];
    dst[2] = gin[m.z * 32 + cb];     dst[3] = gin[m.w * 32 + cb];
    dst[4] = gin[m.x * 32 + cb + 4]; dst[5] = gin[m.y * 32 + cb + 4];
    dst[6] = gin[m.z * 32 + cb + 4]; dst[7] = gin[m.w * 32 + cb + 4];
  };
  auto stage = [&](const f16x8* v, const float4& w, int buf) {
    f16x8 s0 = v[0] * sp8((_Float16)w.x) + v[1] * sp8((_Float16)w.y)
             + v[2] * sp8((_Float16)w.z) + v[3] * sp8((_Float16)w.w);
    f16x8 s1 = v[4] * sp8((_Float16)w.x) + v[5] * sp8((_Float16)w.y)
             + v[6] * sp8((_Float16)w.z) + v[7] * sp8((_Float16)w.w);
    *(f16x8*)(&Sl[buf][pos * SROW2 + cg * 8])      = s0;
    *(f16x8*)(&Sl[buf][pos * SROW2 + 32 + cg * 8]) = s1;
  };
  auto wload_half = [&](int cc, int h) {     // old-chunk 2cc+h -> awv[4h..4h+3]
    const uint4* base = wg4 + (size_t)(2 * cc + h) * 1024 + wbase;
#pragma unroll
    for (int mt = 0; mt < 4; ++mt) awv[h * 4 + mt] = base[mt * 16];
  };

  f32x4 acc[4][4];
#pragma unroll
  for (int mt = 0; mt < 4; ++mt)
#pragma unroll
    for (int nt = 0; nt < 4; ++nt) {
      acc[mt][nt][0] = 0.f; acc[mt][nt][1] = 0.f;
      acc[mt][nt][2] = 0.f; acc[mt][nt][3] = 0.f;
    }

  // ---- prologue: md(tap0), gather chunks 0,1, weights chunk 0, stage 0 ----
  load_md_inputs(0);
  build_md(0, mi_c, mwt_c);
  gather(mi_c, 0, vc[0]);
  wload_half(0, 0); wload_half(0, 1);
  gather(mi_c, 1, vc[1]);
  stage(vc[0], mwt_c, 0);
  barrier_lgkm();

  for (int t = 0; t < 9; ++t) {
#pragma unroll
    for (int j = 0; j < 4; ++j) {          // cc = t*4 + j ; all j-indices fold
      const int cc  = t * 4 + j;
      const int cur = j & 1;

      // gathers for chunk cc+2 -> set cur (freed by stage(cc) last iteration)
      if (j < 2) {
        gather(mi_c, cc + 2, vc[cur]);
      } else if (t < 8) {
        if (j == 2) build_md(t + 1, mi_n, mwt_n);   // inputs loaded at j==0
        gather(mi_n, cc + 2, vc[cur]);
      }
      if (j == 0 && t < 8) load_md_inputs(t + 1);

      // K-half 0: copy A-frags, prefetch next chunk's half 0, MFMA
      {
        f16x8 afr[4];
#pragma unroll
        for (int mt = 0; mt < 4; ++mt) afr[mt] = __builtin_bit_cast(f16x8, awv[mt]);
        if (cc + 1 < NCH2) wload_half(cc + 1, 0);
#pragma unroll
        for (int nt = 0; nt < 4; ++nt) {
          f16x8 bfr = *(const f16x8*)(&Sl[cur][(nt * 16 + lr) * SROW2 + lq * 8]);
#pragma unroll
          for (int mt = 0; mt < 4; ++mt)
            acc[mt][nt] = __builtin_amdgcn_mfma_f32_16x16x32_f16(afr[mt], bfr, acc[mt][nt], 0, 0, 0);
        }
      }
      // K-half 1
      {
        f16x8 afr[4];
#pragma unroll
        for (int mt = 0; mt < 4; ++mt) afr[mt] = __builtin_bit_cast(f16x8, awv[4 + mt]);
        if (cc + 1 < NCH2) wload_half(cc + 1, 1);
#pragma unroll
        for (int nt = 0; nt < 4; ++nt) {
          f16x8 bfr = *(const f16x8*)(&Sl[cur][(nt * 16 + lr) * SROW2 + 32 + lq * 8]);
#pragma unroll
          for (int mt = 0; mt < 4; ++mt)
            acc[mt][nt] = __builtin_amdgcn_mfma_f32_16x16x32_f16(afr[mt], bfr, acc[mt][nt], 0, 0, 0);
        }
      }

      // stage chunk cc+1 (consume set cur^1) into Sl[cur^1]
      if (j < 3) {
        stage(vc[cur ^ 1], mwt_c, cur ^ 1);
      } else if (t < 8) {
        stage(vc[cur ^ 1], mwt_n, cur ^ 1);         // cc+1 starts tap t+1
      }
      barrier_lgkm();
    }
    if (t < 8) { mi_c = mi_n; mwt_c = mwt_n; }
  }

  // ---- epilogue: bias + store ----
#pragma unroll
  for (int mt = 0; mt < 4; ++mt) {
#pragma unroll
    for (int reg = 0; reg < 4; ++reg) {
      int o = wm * 64 + mt * 16 + lq * 4 + reg;
      float bv = bias[o];
      float* op = out + ((size_t)(b * 256 + o)) * 4096 + rp * 64 + lr;
#pragma unroll
      for (int nt = 0; nt < 4; ++nt)
        op[nt * 16] = acc[mt][nt][reg] + bv;
    }
  }
}

extern "C" void kernel_launch(void* const* d_in, const int* in_sizes, int n_in,
                              void* d_out, int out_size, void* d_ws, size_t ws_size,
                              hipStream_t stream) {
  const float* inp    = (const float*)d_in[0];
  const float* offset = (const float*)d_in[1];
  const float* mask   = (const float*)d_in[2];
  const float* weight = (const float*)d_in[3];
  const float* bias   = (const float*)d_in[4];
  float* out = (float*)d_out;

  _Float16* inh = (_Float16*)d_ws;                       // 16.78 MB
  _Float16* wgh = inh + (size_t)Bb * HW * Cc;            // +1.18 MB

  hipLaunchKernelGGL(prep, dim3(TBLK + 288), dim3(256), 0, stream,
                     inp, weight, inh, wgh);
  hipLaunchKernelGGL(dcn_mfma, dim3(Bb, 64), dim3(256), 0, stream,
                     inh, wgh, offset, mask, bias, out);
}

// Round 3
// 141.188 us; speedup vs baseline: 1.0213x; 1.0213x over previous
//
#include <hip/hip_runtime.h>

typedef _Float16 f16x8 __attribute__((ext_vector_type(8)));
typedef float    f32x4 __attribute__((ext_vector_type(4)));

namespace {
constexpr int Bb = 8, Cc = 256, Oo = 256;
constexpr int HW = 4096;                 // 64x64
constexpr int NCH2 = 36;                 // double-chunks of 64 K (4 per tap)
constexpr int SROW2 = 72;                // Sl row stride (f16): 64 + 8 pad
constexpr int TBLK = 512;                // transpose blocks (8 b x 64 px-groups)
}

__device__ inline f16x8 sp8(_Float16 x) { f16x8 r = {x,x,x,x,x,x,x,x}; return r; }

// Raw barrier: drain LDS ops only (stage ds_write visibility), leave global
// gathers / A-frag loads in flight across the barrier (vmcnt uncounted).
__device__ __forceinline__ void barrier_lgkm() {
  asm volatile("s_waitcnt lgkmcnt(0)" ::: "memory");
  __builtin_amdgcn_s_barrier();
}

// ---------- fused pre-kernel (verbatim) ----------
__global__ __launch_bounds__(256)
void prep(const float* __restrict__ in, const float* __restrict__ w,
          _Float16* __restrict__ outh, _Float16* __restrict__ wh) {
  const int bid = blockIdx.x;
  const int t   = threadIdx.x;
  if (bid < TBLK) {
    __shared__ _Float16 Lt[64][264];
    const int b = bid >> 6, pxg = bid & 63;
    const float* src = in + (size_t)b * Cc * HW + pxg * 64;
    const int chb = t & 15, quad = t >> 4;
#pragma unroll
    for (int ci = 0; ci < 16; ++ci) {
      int ch = ci * 16 + chb;
      float4 v = *(const float4*)(src + (size_t)ch * HW + quad * 4);
      Lt[quad * 4 + 0][ch] = (_Float16)v.x;
      Lt[quad * 4 + 1][ch] = (_Float16)v.y;
      Lt[quad * 4 + 2][ch] = (_Float16)v.z;
      Lt[quad * 4 + 3][ch] = (_Float16)v.w;
    }
    __syncthreads();
    _Float16* dst = outh + ((size_t)b * HW + pxg * 64) * Cc;
    const int c8 = t & 31, pxs = t >> 5;
#pragma unroll
    for (int it = 0; it < 8; ++it) {
      int px = it * 8 + pxs;
      f16x8 v = *(const f16x8*)(&Lt[px][c8 * 8]);
      *(f16x8*)(dst + (size_t)px * Cc + c8 * 8) = v;
    }
  } else {
    int tt = (bid - TBLK) * 256 + t;
    int o  = tt & 255;
    int Kb = (tt >> 8) * 8;
    const float* s = w + (size_t)o * 2304;
    f16x8 v;
#pragma unroll
    for (int k8 = 0; k8 < 8; ++k8) {
      int K = Kb + k8;
      int tap = K >> 8, c = K & 255;
      v[k8] = (_Float16)s[c * 9 + tap];
    }
    *(f16x8*)(wh + (size_t)tt * 8) = v;
  }
}

// ---------- main kernel: 2 rows (128 px) per block, 8 waves, M=32/wave ----------
// W (A-frags) read once per chunk per block -> total W L2 traffic halved vs
// the 64-px version (each block now amortizes the 1.18 MB weight stream over
// 2x the pixels). Gather pipeline / chunk schedule identical to R1.
__global__ __launch_bounds__(512, 2)
void dcn_mfma(const _Float16* __restrict__ inh,   // [B][4096][256] fp16 NHWC
              const _Float16* __restrict__ wgh,   // [72][4][256][8] fp16 (A-frag order)
              const float* __restrict__ offset,
              const float* __restrict__ mask,
              const float* __restrict__ bias,
              float* __restrict__ out) {
  __shared__ __align__(16) _Float16 Sl[2][128 * SROW2];  // 36.9 KB

  const int tid = threadIdx.x;
  const int b   = blockIdx.x;   // 0..7  -> linear%8 -> XCD-affine batch
  const int rp  = blockIdx.y;   // 0..31 -> one output row PAIR

  const int pos = tid >> 2, cg = tid & 3;       // pos 0..127, 4 thr/px
  const int ho  = rp * 2 + (pos >> 6), wo = pos & 63;
  const int lane = tid & 63, wm = tid >> 6;     // wm 0..7: M=32 slice per wave
  const int lq = lane >> 4, lr = lane & 15;

  const f16x8* gin = (const f16x8*)(inh + (size_t)b * HW * Cc);
  const uint4* wg4 = (const uint4*)wgh;
  const int    wbase = lq * 256 + wm * 32 + lr;

  int4   mi_c, mi_n = {0,0,0,0};
  float4 mwt_c, mwt_n = {0,0,0,0};
  float  ofy, ofx, msk;
  f16x8  vc[2][8];               // depth-2 corner sets, 8 octets (2 per corner)
  uint4  awv[4];                 // A-fragments in flight (both K-halves, 2 mt)

  auto load_md_inputs = [&](int tap) {
    ofy = offset[(((size_t)b * 18 + 2 * tap)     * 64 + ho) * 64 + wo];
    ofx = offset[(((size_t)b * 18 + 2 * tap + 1) * 64 + ho) * 64 + wo];
    msk = mask  [(((size_t)b * 9  + tap)         * 64 + ho) * 64 + wo];
  };
  auto build_md = [&](int tap, int4& mio, float4& mwo) {
    int ki = tap / 3, kj = tap % 3;
    float y = ofy + (float)(ho - 1 + ki);
    float x = ofx + (float)(wo - 1 + kj);
    float y0f = floorf(y), x0f = floorf(x);
    float ly = y - y0f, lx = x - x0f;
    float hy = 1.f - ly, hx = 1.f - lx;
    int y0 = (int)y0f, x0 = (int)x0f;
    int y1 = y0 + 1, x1 = x0 + 1;
    bool vy0 = (unsigned)y0 < 64u, vy1 = (unsigned)y1 < 64u;
    bool vx0 = (unsigned)x0 < 64u, vx1 = (unsigned)x1 < 64u;
    int cy0 = min(max(y0, 0), 63), cy1 = min(max(y1, 0), 63);
    int cx0 = min(max(x0, 0), 63), cx1 = min(max(x1, 0), 63);
    mwo.x = (vy0 && vx0) ? hy * hx * msk : 0.f;
    mwo.y = (vy0 && vx1) ? hy * lx * msk : 0.f;
    mwo.z = (vy1 && vx0) ? ly * hx * msk : 0.f;
    mwo.w = (vy1 && vx1) ? ly * lx * msk : 0.f;
    mio = make_int4(cy0 * 64 + cx0, cy0 * 64 + cx1, cy1 * 64 + cx0, cy1 * 64 + cx1);
  };
  // gather 64 channels (2 octets per corner) for double-chunk cc
  auto gather = [&](const int4& m, int cc, f16x8* dst) {
    int cb = (cc & 3) * 8 + cg;
    dst[0] = gin[m.x * 32 + cb];     dst[1] = gin[m.y * 32 + cb];
    dst[2] = gin[m.z * 32 + cb];     dst[3] = gin[m.w * 32 + cb];
    dst[4] = gin[m.x * 32 + cb + 4]; dst[5] = gin[m.y * 32 + cb + 4];
    dst[6] = gin[m.z * 32 + cb + 4]; dst[7] = gin[m.w * 32 + cb + 4];
  };
  auto stage = [&](const f16x8* v, const float4& w, int buf) {
    f16x8 s0 = v[0] * sp8((_Float16)w.x) + v[1] * sp8((_Float16)w.y)
             + v[2] * sp8((_Float16)w.z) + v[3] * sp8((_Float16)w.w);
    f16x8 s1 = v[4] * sp8((_Float16)w.x) + v[5] * sp8((_Float16)w.y)
             + v[6] * sp8((_Float16)w.z) + v[7] * sp8((_Float16)w.w);
    *(f16x8*)(&Sl[buf][pos * SROW2 + cg * 8])      = s0;
    *(f16x8*)(&Sl[buf][pos * SROW2 + 32 + cg * 8]) = s1;
  };
  auto wload_half = [&](int cc, int h) {     // chunk-half 2cc+h -> awv[2h..2h+1]
    const uint4* base = wg4 + (size_t)(2 * cc + h) * 1024 + wbase;
#pragma unroll
    for (int mt = 0; mt < 2; ++mt) awv[h * 2 + mt] = base[mt * 16];
  };

  f32x4 acc[2][8];
#pragma unroll
  for (int mt = 0; mt < 2; ++mt)
#pragma unroll
    for (int nt = 0; nt < 8; ++nt) {
      acc[mt][nt][0] = 0.f; acc[mt][nt][1] = 0.f;
      acc[mt][nt][2] = 0.f; acc[mt][nt][3] = 0.f;
    }

  // ---- prologue: md(tap0), gather chunks 0,1, weights chunk 0, stage 0 ----
  load_md_inputs(0);
  build_md(0, mi_c, mwt_c);
  gather(mi_c, 0, vc[0]);
  wload_half(0, 0); wload_half(0, 1);
  gather(mi_c, 1, vc[1]);
  stage(vc[0], mwt_c, 0);
  barrier_lgkm();

  for (int t = 0; t < 9; ++t) {
#pragma unroll
    for (int j = 0; j < 4; ++j) {          // cc = t*4 + j ; all j-indices fold
      const int cc  = t * 4 + j;
      const int cur = j & 1;

      // gathers for chunk cc+2 -> set cur (freed by stage(cc) last iteration)
      if (j < 2) {
        gather(mi_c, cc + 2, vc[cur]);
      } else if (t < 8) {
        if (j == 2) build_md(t + 1, mi_n, mwt_n);   // inputs loaded at j==0
        gather(mi_n, cc + 2, vc[cur]);
      }
      if (j == 0 && t < 8) load_md_inputs(t + 1);

      // K-half 0: copy A-frags, prefetch next chunk's half 0, MFMA
      {
        f16x8 afr[2];
#pragma unroll
        for (int mt = 0; mt < 2; ++mt) afr[mt] = __builtin_bit_cast(f16x8, awv[mt]);
        if (cc + 1 < NCH2) wload_half(cc + 1, 0);
#pragma unroll
        for (int nt = 0; nt < 8; ++nt) {
          f16x8 bfr = *(const f16x8*)(&Sl[cur][(nt * 16 + lr) * SROW2 + lq * 8]);
#pragma unroll
          for (int mt = 0; mt < 2; ++mt)
            acc[mt][nt] = __builtin_amdgcn_mfma_f32_16x16x32_f16(afr[mt], bfr, acc[mt][nt], 0, 0, 0);
        }
      }
      // K-half 1
      {
        f16x8 afr[2];
#pragma unroll
        for (int mt = 0; mt < 2; ++mt) afr[mt] = __builtin_bit_cast(f16x8, awv[2 + mt]);
        if (cc + 1 < NCH2) wload_half(cc + 1, 1);
#pragma unroll
        for (int nt = 0; nt < 8; ++nt) {
          f16x8 bfr = *(const f16x8*)(&Sl[cur][(nt * 16 + lr) * SROW2 + 32 + lq * 8]);
#pragma unroll
          for (int mt = 0; mt < 2; ++mt)
            acc[mt][nt] = __builtin_amdgcn_mfma_f32_16x16x32_f16(afr[mt], bfr, acc[mt][nt], 0, 0, 0);
        }
      }

      // stage chunk cc+1 (consume set cur^1) into Sl[cur^1]
      if (j < 3) {
        stage(vc[cur ^ 1], mwt_c, cur ^ 1);
      } else if (t < 8) {
        stage(vc[cur ^ 1], mwt_n, cur ^ 1);         // cc+1 starts tap t+1
      }
      barrier_lgkm();
    }
    if (t < 8) { mi_c = mi_n; mwt_c = mwt_n; }
  }

  // ---- epilogue: bias + store ----
  // C/D 16x16 layout: col(px)=lr, row(o)=lq*4+reg. px = nt*16+lr spans both
  // rows of the pair: out offset rp*128 + nt*16 + lr covers (row rp*2 + nt/4).
#pragma unroll
  for (int mt = 0; mt < 2; ++mt) {
#pragma unroll
    for (int reg = 0; reg < 4; ++reg) {
      int o = wm * 32 + mt * 16 + lq * 4 + reg;
      float bv = bias[o];
      float* op = out + ((size_t)(b * 256 + o)) * 4096 + rp * 128 + lr;
#pragma unroll
      for (int nt = 0; nt < 8; ++nt)
        op[nt * 16] = acc[mt][nt][reg] + bv;
    }
  }
}

extern "C" void kernel_launch(void* const* d_in, const int* in_sizes, int n_in,
                              void* d_out, int out_size, void* d_ws, size_t ws_size,
                              hipStream_t stream) {
  const float* inp    = (const float*)d_in[0];
  const float* offset = (const float*)d_in[1];
  const float* mask   = (const float*)d_in[2];
  const float* weight = (const float*)d_in[3];
  const float* bias   = (const float*)d_in[4];
  float* out = (float*)d_out;

  _Float16* inh = (_Float16*)d_ws;                       // 16.78 MB
  _Float16* wgh = inh + (size_t)Bb * HW * Cc;            // +1.18 MB

  hipLaunchKernelGGL(prep, dim3(TBLK + 288), dim3(256), 0, stream,
                     inp, weight, inh, wgh);
  hipLaunchKernelGGL(dcn_mfma, dim3(Bb, 32), dim3(512), 0, stream,
                     inh, wgh, offset, mask, bias, out);
}